// Round 6
// baseline (753.369 us; speedup 1.0000x reference)
//
#include <hip/hip_runtime.h>
#include <hip/hip_bf16.h>

typedef __bf16 bf16_t;
typedef __bf16 bf16x8 __attribute__((ext_vector_type(8)));
typedef __bf16 bf16x4 __attribute__((ext_vector_type(4)));
typedef float f32x4 __attribute__((ext_vector_type(4)));

// ---------------------------------------------------------------------------
// Sizes (fixed): B = 16384, D = H = 512
//   A_big : [B][2048] bf16 = [x_re | x_im | h_re | h_im]
//   W1t   : [3072][2048] bf16 (B^T layout). Columns: [0,1024) z (K=2048),
//           [1024,2048) r (K=2048), [2048,3072) px2 (K=1024). re/im interleaved.
//   W2t   : [1024][1024] bf16, ph columns interleaved, K=1024 over [rh_re|rh_im]
//   A2    : [B][1024] bf16 = [rh_re | rh_im]
//   zbuf  : [B][1024] bf16 interleaved (z in [0,1]; bf16 quant <= 4e-3, safe)
//   t (= px2+bx2+bh2) staged fp32 in d_out, overwritten by final in GEMM2.
// ---------------------------------------------------------------------------

__device__ __forceinline__ void gl_lds16(const bf16_t* g, bf16_t* l) {
  __builtin_amdgcn_global_load_lds(
      (const __attribute__((address_space(1))) void*)g,
      (__attribute__((address_space(3))) void*)l, 16, 0, 0);
}

__device__ __forceinline__ float fast_sigmoid(float x) {
  return 1.0f / (1.0f + __expf(-x));
}

// ---------------------------------------------------------------------------
__global__ void pack_A(const float* __restrict__ x_re, const float* __restrict__ x_im,
                       const float* __restrict__ h_re, const float* __restrict__ h_im,
                       bf16_t* __restrict__ A) {
  int q = blockIdx.x * blockDim.x + threadIdx.x;   // 8388608 quads total
  int i4 = q << 2;
  int b = i4 >> 11;
  int k = i4 & 2047;
  int seg = k >> 9;
  int off = k & 511;
  const float* s = (seg == 0) ? x_re : (seg == 1) ? x_im : (seg == 2) ? h_re : h_im;
  const float4 v = *(const float4*)(s + (size_t)b * 512 + off);
  bf16x4 o = { (bf16_t)v.x, (bf16_t)v.y, (bf16_t)v.z, (bf16_t)v.w };
  *(bf16x4*)(A + (size_t)b * 2048 + k) = o;
}

// ---------------------------------------------------------------------------
__global__ void pack_W(const float* __restrict__ Wx_re, const float* __restrict__ Wx_im,
                       const float* __restrict__ Wh_re, const float* __restrict__ Wh_im,
                       bf16_t* __restrict__ W1t, bf16_t* __restrict__ W2t) {
  int q = blockIdx.x * blockDim.x + threadIdx.x;   // 1572864 quads total
  int n, k2, g, j, p;
  const float *Wre, *Wim;
  bf16_t* dst;
  if (q < 1048576) {                       // W1t rows [0,2048): z and r, k2 in [0,2048)
    n = q >> 9; k2 = (q & 511) << 2;
    g = n >> 10; j = (n & 1023) >> 1; p = n & 1;
    int pair = k2 >> 10;                   // 0: x-part (Wx), 1: h-part (Wh)
    Wre = pair ? Wh_re : Wx_re;
    Wim = pair ? Wh_im : Wx_im;
    dst = W1t + (size_t)n * 2048 + k2;
  } else if (q < 1048576 + 262144) {       // W1t rows [2048,3072): px2, k2 in [0,1024)
    int q2 = q - 1048576;
    n = 2048 + (q2 >> 8); k2 = (q2 & 255) << 2;
    g = 2; j = (n - 2048) >> 1; p = n & 1;
    Wre = Wx_re; Wim = Wx_im;
    dst = W1t + (size_t)n * 2048 + k2;
  } else {                                 // W2t rows [0,1024), k2 in [0,1024)
    int q3 = q - (1048576 + 262144);
    n = q3 >> 8; k2 = (q3 & 255) << 2;
    g = 2; j = n >> 1; p = n & 1;
    Wre = Wh_re; Wim = Wh_im;
    dst = W2t + (size_t)n * 1024 + k2;
  }
  int klocal = k2 & 1023;
  int half = klocal >> 9;                  // 0: real-operand half, 1: imag-operand half
  int off = klocal & 511;
  size_t sidx = ((size_t)g * 512 + j) * 512 + off;
  const float* s = (half == 0) ? (p ? Wim : Wre) : (p ? Wre : Wim);
  float sgn = (half == 1 && p == 0) ? -1.0f : 1.0f;
  float4 v = *(const float4*)(s + sidx);
  bf16x4 o = { (bf16_t)(sgn * v.x), (bf16_t)(sgn * v.y),
               (bf16_t)(sgn * v.z), (bf16_t)(sgn * v.w) };
  *(bf16x4*)dst = o;
}

// ---------------------------------------------------------------------------
// 128x128 tile, BK=64, 256 threads (4 waves, 2x2 of 64x64), LDS = 2 x 32 KB
// = 64 KiB -> TWO blocks co-resident per CU. Each SIMD hosts one wave of each
// block: two independent instruction streams, so one block's boundary drain
// (vmcnt wait / barrier skew) is filled by the other block's MFMA (the m114
// cross-block overlap mechanism) -- the one structural lever 5 rounds of
// in-block schedule variants (all ~23% MfmaUtil) could not reach.
// Per K-tile: 2 phases of {8 JIT ds_read_b128 -> 16 MFMA (setprio-wrapped)};
// full kt+1 staging (8 global_load_lds) issued at phase-1 start into buf^1,
// so the single boundary vmcnt(0) waits only on ~1.5-phase-old loads; one
// barrier per K-tile. LDS swizzle: 16B-chunk c ^= (r&7), applied on the
// global SOURCE address (gl_lds writes linearly) and on the ds_read address
// (same involution) -- measured 0 bank conflicts.
// Grid decode: xcd = bid&7 gets a contiguous (mtile,ntile) sub-grid of
// 16 mtiles x all ntiles, so A-slabs (512 KB) and W-slabs are L2-resident.
template <int MODE>
__launch_bounds__(256, 2)
__global__ void gemm_fused(const bf16_t* __restrict__ A, const bf16_t* __restrict__ W,
                           int LDA, int LDW,
                           bf16_t* __restrict__ zbuf, bf16_t* __restrict__ A2,
                           float* __restrict__ outbuf,
                           const float* __restrict__ h_re, const float* __restrict__ h_im,
                           const float* __restrict__ bx_re, const float* __restrict__ bx_im,
                           const float* __restrict__ bh_re, const float* __restrict__ bh_im) {
  __shared__ __align__(16) bf16_t As[2][128 * 64];
  __shared__ __align__(16) bf16_t Bs[2][128 * 64];

  const int bid = blockIdx.x;
  const int xcd = bid & 7;
  const int idx = bid >> 3;               // MODE1: 0..383, MODE2: 0..127
  const int NT = (MODE == 1) ? 24 : 8;    // ntiles of 128 cols
  const int ntile = idx % NT;
  const int mtile = (xcd << 4) + idx / NT;   // 0..127
  const int m0 = mtile * 128;
  const int n0 = ntile * 128;
  const int region = (MODE == 1) ? (ntile >> 3) : 0;    // 0:z 1:r 2:px2
  const int KEND = (MODE == 1) ? ((region < 2) ? 2048 : 1024) : 1024;
  const int nKT = KEND >> 6;              // K-tiles of 64

  const int tid = threadIdx.x;
  const int lane = tid & 63;
  const int w = tid >> 6;                 // 0..3
  const int wr = w >> 1;                  // 0..1 (M)
  const int wc = w & 1;                   // 0..1 (N)

  // staging: sweep s covers rows [32s, 32s+32); thread -> (row rb, chunk cc)
  const int rb = tid >> 3;                // 0..31
  const int cc = tid & 7;                 // 16B chunk within 128B row
  const int cs = cc ^ (rb & 7);           // source-side swizzle
  const bf16_t* Ag = A + (size_t)(m0 + rb) * LDA + cs * 8;
  const bf16_t* Wg = W + (size_t)(n0 + rb) * LDW + cs * 8;

#define STAGE_A(s, bufi, kt2) \
  gl_lds16(Ag + (size_t)(s) * 32 * LDA + (kt2) * 64, &As[bufi][tid * 8 + (s) * 2048])
#define STAGE_B(s, bufi, kt2) \
  gl_lds16(Wg + (size_t)(s) * 32 * LDW + (kt2) * 64, &Bs[bufi][tid * 8 + (s) * 2048])

  const int quad = lane >> 4, lrow = lane & 15;
  int aOff[4], bOff[4];                   // k0 offsets; k1 = off ^ 32
#pragma unroll
  for (int mt = 0; mt < 4; ++mt) {
    const int r = wr * 64 + mt * 16 + lrow;
    aOff[mt] = r * 64 + ((quad ^ (r & 7)) << 3);
  }
#pragma unroll
  for (int nt = 0; nt < 4; ++nt) {
    const int r = wc * 64 + nt * 16 + lrow;
    bOff[nt] = r * 64 + ((quad ^ (r & 7)) << 3);
  }

  f32x4 acc[4][4] = {};

  // prologue: stage KT0 into buf0
#pragma unroll
  for (int s = 0; s < 4; ++s) STAGE_B(s, 0, 0);
#pragma unroll
  for (int s = 0; s < 4; ++s) STAGE_A(s, 0, 0);
  asm volatile("s_waitcnt vmcnt(0)" ::: "memory");
  __builtin_amdgcn_s_barrier();

  for (int kt = 0; kt < nKT; ++kt) {
    const int b = kt & 1;
    const bf16_t* Ab = As[b];
    const bf16_t* Bb = Bs[b];
    const bool s1 = (kt + 1 < nKT);

    bf16x8 ak[4], bk[4];

    // ---- phase 1 (k0): JIT reads + full staging of kt+1 into buf^1 ----
#pragma unroll
    for (int i = 0; i < 4; ++i) bk[i] = *(const bf16x8*)(Bb + bOff[i]);
#pragma unroll
    for (int i = 0; i < 4; ++i) ak[i] = *(const bf16x8*)(Ab + aOff[i]);
    if (s1) {
#pragma unroll
      for (int s = 0; s < 4; ++s) STAGE_B(s, b ^ 1, kt + 1);
#pragma unroll
      for (int s = 0; s < 4; ++s) STAGE_A(s, b ^ 1, kt + 1);
    }
    __builtin_amdgcn_s_setprio(1);
#pragma unroll
    for (int i = 0; i < 4; ++i)
#pragma unroll
      for (int j2 = 0; j2 < 4; ++j2)
        acc[i][j2] = __builtin_amdgcn_mfma_f32_16x16x32_bf16(ak[i], bk[j2], acc[i][j2], 0, 0, 0);
    __builtin_amdgcn_s_setprio(0);

    // ---- phase 2 (k1): JIT reads; MFMA ----
#pragma unroll
    for (int i = 0; i < 4; ++i) bk[i] = *(const bf16x8*)(Bb + (bOff[i] ^ 32));
#pragma unroll
    for (int i = 0; i < 4; ++i) ak[i] = *(const bf16x8*)(Ab + (aOff[i] ^ 32));
    __builtin_amdgcn_s_setprio(1);
#pragma unroll
    for (int i = 0; i < 4; ++i)
#pragma unroll
      for (int j2 = 0; j2 < 4; ++j2)
        acc[i][j2] = __builtin_amdgcn_mfma_f32_16x16x32_bf16(ak[i], bk[j2], acc[i][j2], 0, 0, 0);
    __builtin_amdgcn_s_setprio(0);

    // ---- boundary: kt+1's 8 loads (issued ~1.5 phases ago) must land ----
    if (s1) asm volatile("s_waitcnt vmcnt(0)" ::: "memory");
    __builtin_amdgcn_s_barrier();
  }
#undef STAGE_A
#undef STAGE_B

  // ---- epilogue ----
  // C/D layout: col = lane&15, row = quad*4 + reg  [verified m89/m91]
#pragma unroll
  for (int mt = 0; mt < 4; ++mt) {
#pragma unroll
    for (int nt = 0; nt < 4; ++nt) {
#pragma unroll
      for (int rg = 0; rg < 4; ++rg) {
        const int m = m0 + wr * 64 + mt * 16 + quad * 4 + rg;
        const int n = n0 + wc * 64 + nt * 16 + lrow;
        float v = acc[mt][nt][rg];
        const int p = n & 1;               // 0 = real component, 1 = imag

        if (MODE == 1) {
          const int cj = n & 1023;
          const int j = cj >> 1;
          const float bias = p ? (bx_im[region * 512 + j] + bh_im[region * 512 + j])
                               : (bx_re[region * 512 + j] + bh_re[region * 512 + j]);
          const float val = v + bias;
          if (region == 0) {               // z gate (bf16 store)
            zbuf[(size_t)m * 1024 + cj] = (bf16_t)fast_sigmoid(val);
          } else if (region == 1) {        // r gate -> rh = r * h (complex)
            float rv = fast_sigmoid(val);
            float ro = __shfl_xor(rv, 1, 64);
            float hp = p ? h_im[(size_t)m * 512 + j] : h_re[(size_t)m * 512 + j];
            float ho = __shfl_xor(hp, 1, 64);
            float rh = (p == 0) ? (rv * hp - ro * ho) : (ro * hp + rv * ho);
            A2[(size_t)m * 1024 + p * 512 + j] = (bf16_t)rh;
          } else {                         // px2 + bx2 + bh2 -> staged in d_out
            outbuf[(size_t)m * 1024 + cj] = val;
          }
        } else {
          // MODE 2: u = t + ph ; h_tilde = tanh(|u|)/|u| * u ; combine
          const int j = n >> 1;
          float tv = outbuf[(size_t)m * 1024 + n];
          float u = tv + v;
          float uo = __shfl_xor(u, 1, 64);
          float mag = sqrtf(u * u + uo * uo);
          float mm = fminf(mag, 20.0f);
          float e = __expf(2.0f * mm);
          float th = (e - 1.0f) / (e + 1.0f);
          float s = (mag == 0.0f) ? 0.0f : (th / mag);
          float hto = s * u;               // own component of h_tilde
          float htd = s * uo;              // other component
          float zv = (float)zbuf[(size_t)m * 1024 + n];
          float zo = __shfl_xor(zv, 1, 64);
          float hp = p ? h_im[(size_t)m * 512 + j] : h_re[(size_t)m * 512 + j];
          float ho = __shfl_xor(hp, 1, 64);
          float res;
          if (p == 0)
            res = (1.0f - zv) * hp + zo * ho + zv * hto - zo * htd;
          else
            res = (1.0f - zo) * hp - zv * ho + zo * hto + zv * htd;
          outbuf[(size_t)m * 1024 + n] = res;
        }
      }
    }
  }
}

// ---------------------------------------------------------------------------
extern "C" void kernel_launch(void* const* d_in, const int* in_sizes, int n_in,
                              void* d_out, int out_size, void* d_ws, size_t ws_size,
                              hipStream_t stream) {
  const float* x_re  = (const float*)d_in[0];
  const float* x_im  = (const float*)d_in[1];
  const float* h_re  = (const float*)d_in[2];
  const float* h_im  = (const float*)d_in[3];
  const float* Wx_re = (const float*)d_in[4];
  const float* Wx_im = (const float*)d_in[5];
  const float* Wh_re = (const float*)d_in[6];
  const float* Wh_im = (const float*)d_in[7];
  const float* bx_re = (const float*)d_in[8];
  const float* bx_im = (const float*)d_in[9];
  const float* bh_re = (const float*)d_in[10];
  const float* bh_im = (const float*)d_in[11];
  float* out = (float*)d_out;

  char* ws = (char*)d_ws;
  bf16_t* A_big = (bf16_t*)(ws);                         // 67108864 B
  bf16_t* W1t   = (bf16_t*)(ws + 67108864);              // 12582912 B
  bf16_t* W2t   = (bf16_t*)(ws + 79691776);              //  2097152 B
  bf16_t* A2    = (bf16_t*)(ws + 81788928);              // 33554432 B
  bf16_t* zbuf  = (bf16_t*)(ws + 115343360);             // 33554432 B  (end: 148897792)

  pack_A<<<32768, 256, 0, stream>>>(x_re, x_im, h_re, h_im, A_big);
  pack_W<<<6144, 256, 0, stream>>>(Wx_re, Wx_im, Wh_re, Wh_im, W1t, W2t);
  gemm_fused<1><<<3072, 256, 0, stream>>>(A_big, W1t, 2048, 2048,
      zbuf, A2, out, h_re, h_im, bx_re, bx_im, bh_re, bh_im);
  gemm_fused<2><<<1024, 256, 0, stream>>>(A2, W2t, 1024, 1024,
      zbuf, A2, out, h_re, h_im, bx_re, bx_im, bh_re, bh_im);
}

// Round 7
// 606.341 us; speedup vs baseline: 1.2425x; 1.2425x over previous
//
#include <hip/hip_runtime.h>
#include <hip/hip_bf16.h>

typedef __bf16 bf16_t;
typedef __bf16 bf16x8 __attribute__((ext_vector_type(8)));
typedef __bf16 bf16x4 __attribute__((ext_vector_type(4)));
typedef float f32x4 __attribute__((ext_vector_type(4)));

// ---------------------------------------------------------------------------
// Sizes (fixed): B = 16384, D = H = 512
//   A_big : [B][2048] bf16 = [x_re | x_im | h_re | h_im]
//   W1t   : [3072][2048] bf16 (B^T layout), re/im-interleaved output rows:
//           rows [0,1024) z, [1024,2048) r, [2048,3072) u. ALL K=2048:
//           pair 0 = Wx[g] over x-cols, pair 1 = Wh[g] over h-cols.
//           For the u rows (g=2) the "h" operand is rh (stored in A2).
//   A2    : [B][1024] bf16 = [rh_re | rh_im]   (written by gemm1 r-region)
//   zbuf  : [B][1024] bf16 interleaved (z in [0,1]; bf16 quant <= 4e-3, safe)
// u = x.Wx[2] + rh.Wh[2] + b is ONE K=2048 GEMM (gemm2): staging reads
// k-chunks [0,16) from A_big (x part) and [16,32) from A2 (rh part).
// The old fp32 outbuf round-trip (64 MB write + 64 MB read) is eliminated.
// ---------------------------------------------------------------------------

__device__ __forceinline__ void gl_lds16(const bf16_t* g, bf16_t* l) {
  __builtin_amdgcn_global_load_lds(
      (const __attribute__((address_space(1))) void*)g,
      (__attribute__((address_space(3))) void*)l, 16, 0, 0);
}

__device__ __forceinline__ float fast_sigmoid(float x) {
  return 1.0f / (1.0f + __expf(-x));
}

// ---------------------------------------------------------------------------
__global__ void pack_A(const float* __restrict__ x_re, const float* __restrict__ x_im,
                       const float* __restrict__ h_re, const float* __restrict__ h_im,
                       bf16_t* __restrict__ A) {
  int q = blockIdx.x * blockDim.x + threadIdx.x;   // 8388608 quads total
  int i4 = q << 2;
  int b = i4 >> 11;
  int k = i4 & 2047;
  int seg = k >> 9;
  int off = k & 511;
  const float* s = (seg == 0) ? x_re : (seg == 1) ? x_im : (seg == 2) ? h_re : h_im;
  const float4 v = *(const float4*)(s + (size_t)b * 512 + off);
  bf16x4 o = { (bf16_t)v.x, (bf16_t)v.y, (bf16_t)v.z, (bf16_t)v.w };
  *(bf16x4*)(A + (size_t)b * 2048 + k) = o;
}

// ---------------------------------------------------------------------------
// W1t only: 3072 rows x 2048 cols, unified K=2048 complex layout for all
// three gates g = n>>10 (0:z 1:r 2:u). 1572864 quads, grid 6144x256.
__global__ void pack_W(const float* __restrict__ Wx_re, const float* __restrict__ Wx_im,
                       const float* __restrict__ Wh_re, const float* __restrict__ Wh_im,
                       bf16_t* __restrict__ W1t) {
  int q = blockIdx.x * blockDim.x + threadIdx.x;
  int n = q >> 9;                          // 0..3071
  int k2 = (q & 511) << 2;                 // 0..2044
  int g = n >> 10;                         // gate 0,1,2
  int j = (n & 1023) >> 1;
  int p = n & 1;
  int pair = k2 >> 10;                     // 0: x-part (Wx[g]), 1: h-part (Wh[g])
  const float* Wre = pair ? Wh_re : Wx_re;
  const float* Wim = pair ? Wh_im : Wx_im;
  int klocal = k2 & 1023;
  int half = klocal >> 9;                  // 0: real-operand half, 1: imag-operand half
  int off = klocal & 511;
  size_t sidx = ((size_t)g * 512 + j) * 512 + off;
  const float* s = (half == 0) ? (p ? Wim : Wre) : (p ? Wre : Wim);
  float sgn = (half == 1 && p == 0) ? -1.0f : 1.0f;
  float4 v = *(const float4*)(s + sidx);
  bf16x4 o = { (bf16_t)(sgn * v.x), (bf16_t)(sgn * v.y),
               (bf16_t)(sgn * v.z), (bf16_t)(sgn * v.w) };
  *(bf16x4*)(W1t + (size_t)n * 2048 + k2) = o;
}

// ---------------------------------------------------------------------------
// 256x256 tile, BK=64, 512 threads (8 waves, 2M x 4N; per-wave 128x64 output),
// 16x16x32 MFMA. 4-phase schedule, 2 K-tiles pipelined (round-5 structure,
// best measured): phase q = { JIT ds_reads ; 2 x global_load_lds of kt+1
// into buf^1 ; barrier ; lgkmcnt(0) ; setprio(1) ; 16 MFMA ; setprio(0) ;
// [counted vmcnt at q1/q4] ; barrier }. Staging order [B01,B23,A02,A13];
// vmcnt invariant: entering KT t exactly A13(t) outstanding; end-q1 vmcnt(2)
// retires it; end-q4 vmcnt(2) retires B01,B23,A02(t+1), leaves A13(t+1).
// LDS swizzle: 16B-chunk c ^= (r&7), source-side for gl_lds + on ds_read
// (measured 0 bank conflicts). Grid: xcd=bid&7, idx=bid>>3; ntile=idx>>3,
// mtile=(xcd<<3)+(idx&7). MODE1: 512 blocks (z+r), MODE2: 256 blocks (u).
// MODE2 staging: k-chunk kt2<16 -> A_big x-cols; kt2>=16 -> A2 rh-cols.
template <int MODE>
__launch_bounds__(512, 2)
__global__ void gemm_fused(const bf16_t* __restrict__ A, const bf16_t* __restrict__ W,
                           int LDA, int LDW,
                           bf16_t* __restrict__ zbuf, bf16_t* __restrict__ A2,
                           float* __restrict__ outbuf,
                           const float* __restrict__ h_re, const float* __restrict__ h_im,
                           const float* __restrict__ bx_re, const float* __restrict__ bx_im,
                           const float* __restrict__ bh_re, const float* __restrict__ bh_im) {
  __shared__ __align__(16) bf16_t As[2][256 * 64];
  __shared__ __align__(16) bf16_t Bs[2][256 * 64];

  const int bid = blockIdx.x;
  const int xcd = bid & 7;
  const int idx = bid >> 3;               // MODE1: 0..63, MODE2: 0..31
  const int ntile = idx >> 3;             // MODE1: 0..7, MODE2: 0..3
  const int mtile = (xcd << 3) + (idx & 7);  // 0..63
  const int m0 = mtile * 256;
  const int n0 = ntile * 256;
  const int region = (MODE == 1) ? (ntile >> 2) : 2;    // 0:z 1:r 2:u
  const int nKT = 32;                     // K = 2048 for all gates

  const int tid = threadIdx.x;
  const int lane = tid & 63;
  const int w = tid >> 6;                 // 0..7
  const int wr = w >> 2;                  // 0..1 (M)
  const int wc = w & 3;                   // 0..3 (N)

  // staging: sweep s covers rows [64s, 64s+64); thread -> (row rb, chunk cc)
  const int rb = tid >> 3;                // 0..63
  const int cc = tid & 7;                 // 16B chunk within 128B row
  const int cs = cc ^ (rb & 7);           // source-side swizzle
  const bf16_t* Ag = A + (size_t)(m0 + rb) * LDA + cs * 8;
  const bf16_t* Rg = A2 + (size_t)(m0 + rb) * 1024 + cs * 8;   // rh rows (MODE2)
  const bf16_t* Wg = W + (size_t)(n0 + rb) * LDW + cs * 8;

#define STAGE_A(s, bufi, kt2) do {                                            \
    const bf16_t* _g;                                                         \
    if (MODE == 2 && (kt2) >= 16)                                             \
      _g = Rg + (size_t)(s) * 64 * 1024 + ((kt2) - 16) * 64;                  \
    else                                                                      \
      _g = Ag + (size_t)(s) * 64 * LDA + (kt2) * 64;                          \
    gl_lds16(_g, &As[bufi][tid * 8 + (s) * 4096]);                            \
  } while (0)
#define STAGE_B(s, bufi, kt2) \
  gl_lds16(Wg + (size_t)(s) * 64 * LDW + (kt2) * 64, &Bs[bufi][tid * 8 + (s) * 4096])

  const int quad = lane >> 4, lrow = lane & 15;
  int aOff[8], bOff[4];                   // k0 offsets; k1 = off ^ 32
#pragma unroll
  for (int mt = 0; mt < 8; ++mt) {
    const int r = wr * 128 + mt * 16 + lrow;
    aOff[mt] = r * 64 + ((quad ^ (r & 7)) << 3);
  }
#pragma unroll
  for (int nt = 0; nt < 4; ++nt) {
    const int r = wc * 64 + nt * 16 + lrow;
    bOff[nt] = r * 64 + ((quad ^ (r & 7)) << 3);
  }

  f32x4 acc[8][4] = {};

  // prologue: KT0 fully, ordered so the LAST two loads are A13(0):
  // [B0,B1,B2,B3, A0,A2, A1,A3]; vmcnt(2) retires B0-3,A0,A2 (needed q1),
  // leaves A13(0) outstanding -> steady-state invariant from the start.
  STAGE_B(0, 0, 0); STAGE_B(1, 0, 0); STAGE_B(2, 0, 0); STAGE_B(3, 0, 0);
  STAGE_A(0, 0, 0); STAGE_A(2, 0, 0);
  STAGE_A(1, 0, 0); STAGE_A(3, 0, 0);
  asm volatile("s_waitcnt vmcnt(2)" ::: "memory");
  __builtin_amdgcn_s_barrier();

  for (int kt = 0; kt < nKT; ++kt) {
    const int b = kt & 1;
    const bf16_t* Ab = As[b];
    const bf16_t* Bb = Bs[b];
    const bool s1 = (kt + 1 < nKT);

    bf16x8 bk[4], bk1[4], af[4];

    // ---- q1: JIT reads A-lo k0 (4) + B k0 (4); stage B01(kt+1) ----
#pragma unroll
    for (int nt = 0; nt < 4; ++nt) bk[nt] = *(const bf16x8*)(Bb + bOff[nt]);
#pragma unroll
    for (int i = 0; i < 4; ++i) af[i] = *(const bf16x8*)(Ab + aOff[i]);
    if (s1) { STAGE_B(0, b ^ 1, kt + 1); STAGE_B(1, b ^ 1, kt + 1); }
    __builtin_amdgcn_s_barrier();
    asm volatile("s_waitcnt lgkmcnt(0)" ::: "memory");
    __builtin_amdgcn_s_setprio(1);
#pragma unroll
    for (int i = 0; i < 4; ++i)
#pragma unroll
      for (int nt = 0; nt < 4; ++nt)
        acc[i][nt] = __builtin_amdgcn_mfma_f32_16x16x32_bf16(af[i], bk[nt], acc[i][nt], 0, 0, 0);
    __builtin_amdgcn_s_setprio(0);
    // retire A13(kt) (needed by q2); leave B01(kt+1) in flight
    if (s1) asm volatile("s_waitcnt vmcnt(2)" ::: "memory");
    else    asm volatile("s_waitcnt vmcnt(0)" ::: "memory");
    __builtin_amdgcn_s_barrier();

    // ---- q2: JIT reads A-hi k0 (4); B reused from regs; stage B23(kt+1) ----
#pragma unroll
    for (int i = 0; i < 4; ++i) af[i] = *(const bf16x8*)(Ab + aOff[4 + i]);
    if (s1) { STAGE_B(2, b ^ 1, kt + 1); STAGE_B(3, b ^ 1, kt + 1); }
    __builtin_amdgcn_s_barrier();
    asm volatile("s_waitcnt lgkmcnt(0)" ::: "memory");
    __builtin_amdgcn_s_setprio(1);
#pragma unroll
    for (int i = 0; i < 4; ++i)
#pragma unroll
      for (int nt = 0; nt < 4; ++nt)
        acc[4 + i][nt] = __builtin_amdgcn_mfma_f32_16x16x32_bf16(af[i], bk[nt], acc[4 + i][nt], 0, 0, 0);
    __builtin_amdgcn_s_setprio(0);
    __builtin_amdgcn_s_barrier();

    // ---- q3: JIT reads A-lo k1 (4) + B k1 (4); stage A02(kt+1) ----
#pragma unroll
    for (int nt = 0; nt < 4; ++nt) bk1[nt] = *(const bf16x8*)(Bb + (bOff[nt] ^ 32));
#pragma unroll
    for (int i = 0; i < 4; ++i) af[i] = *(const bf16x8*)(Ab + (aOff[i] ^ 32));
    if (s1) { STAGE_A(0, b ^ 1, kt + 1); STAGE_A(2, b ^ 1, kt + 1); }
    __builtin_amdgcn_s_barrier();
    asm volatile("s_waitcnt lgkmcnt(0)" ::: "memory");
    __builtin_amdgcn_s_setprio(1);
#pragma unroll
    for (int i = 0; i < 4; ++i)
#pragma unroll
      for (int nt = 0; nt < 4; ++nt)
        acc[i][nt] = __builtin_amdgcn_mfma_f32_16x16x32_bf16(af[i], bk1[nt], acc[i][nt], 0, 0, 0);
    __builtin_amdgcn_s_setprio(0);
    __builtin_amdgcn_s_barrier();

    // ---- q4: JIT reads A-hi k1 (4); stage A13(kt+1) ----
#pragma unroll
    for (int i = 0; i < 4; ++i) af[i] = *(const bf16x8*)(Ab + (aOff[4 + i] ^ 32));
    if (s1) { STAGE_A(1, b ^ 1, kt + 1); STAGE_A(3, b ^ 1, kt + 1); }
    __builtin_amdgcn_s_barrier();
    asm volatile("s_waitcnt lgkmcnt(0)" ::: "memory");
    __builtin_amdgcn_s_setprio(1);
#pragma unroll
    for (int i = 0; i < 4; ++i)
#pragma unroll
      for (int nt = 0; nt < 4; ++nt)
        acc[4 + i][nt] = __builtin_amdgcn_mfma_f32_16x16x32_bf16(af[i], bk1[nt], acc[4 + i][nt], 0, 0, 0);
    __builtin_amdgcn_s_setprio(0);
    // retire B01,B23,A02 of kt+1 (needed by next q1); leave A13(kt+1)
    if (s1) asm volatile("s_waitcnt vmcnt(2)" ::: "memory");
    __builtin_amdgcn_s_barrier();
  }
#undef STAGE_A
#undef STAGE_B

  // ---- epilogue ----
  // C/D layout: col = lane&15, row = quad*4 + reg  [verified m89/m91]
#pragma unroll
  for (int mt = 0; mt < 8; ++mt) {
#pragma unroll
    for (int nt = 0; nt < 4; ++nt) {
#pragma unroll
      for (int rg = 0; rg < 4; ++rg) {
        const int m = m0 + wr * 128 + mt * 16 + quad * 4 + rg;
        const int n = n0 + wc * 64 + nt * 16 + lrow;
        float v = acc[mt][nt][rg];
        const int p = n & 1;               // 0 = real component, 1 = imag
        const int cj = n & 1023;
        const int j = cj >> 1;
        const float bias = p ? (bx_im[region * 512 + j] + bh_im[region * 512 + j])
                             : (bx_re[region * 512 + j] + bh_re[region * 512 + j]);
        const float val = v + bias;

        if (MODE == 1) {
          if (region == 0) {               // z gate (bf16 store)
            zbuf[(size_t)m * 1024 + cj] = (bf16_t)fast_sigmoid(val);
          } else {                         // r gate -> rh = r * h (complex)
            float rv = fast_sigmoid(val);
            float ro = __shfl_xor(rv, 1, 64);
            float hp = p ? h_im[(size_t)m * 512 + j] : h_re[(size_t)m * 512 + j];
            float ho = __shfl_xor(hp, 1, 64);
            float rh = (p == 0) ? (rv * hp - ro * ho) : (ro * hp + rv * ho);
            A2[(size_t)m * 1024 + p * 512 + j] = (bf16_t)rh;
          }
        } else {
          // MODE 2: u = val ; h_tilde = tanh(|u|)/|u| * u ; combine
          float u = val;
          float uo = __shfl_xor(u, 1, 64);
          float mag = sqrtf(u * u + uo * uo);
          float mm = fminf(mag, 20.0f);
          float e = __expf(2.0f * mm);
          float th = (e - 1.0f) / (e + 1.0f);
          float s = (mag == 0.0f) ? 0.0f : (th / mag);
          float hto = s * u;               // own component of h_tilde
          float htd = s * uo;              // other component
          float zv = (float)zbuf[(size_t)m * 1024 + cj];
          float zo = __shfl_xor(zv, 1, 64);
          float hp = p ? h_im[(size_t)m * 512 + j] : h_re[(size_t)m * 512 + j];
          float ho = __shfl_xor(hp, 1, 64);
          float res;
          if (p == 0)
            res = (1.0f - zv) * hp + zo * ho + zv * hto - zo * htd;
          else
            res = (1.0f - zo) * hp - zv * ho + zo * hto + zv * htd;
          outbuf[(size_t)m * 1024 + cj] = res;
        }
      }
    }
  }
}

// ---------------------------------------------------------------------------
extern "C" void kernel_launch(void* const* d_in, const int* in_sizes, int n_in,
                              void* d_out, int out_size, void* d_ws, size_t ws_size,
                              hipStream_t stream) {
  const float* x_re  = (const float*)d_in[0];
  const float* x_im  = (const float*)d_in[1];
  const float* h_re  = (const float*)d_in[2];
  const float* h_im  = (const float*)d_in[3];
  const float* Wx_re = (const float*)d_in[4];
  const float* Wx_im = (const float*)d_in[5];
  const float* Wh_re = (const float*)d_in[6];
  const float* Wh_im = (const float*)d_in[7];
  const float* bx_re = (const float*)d_in[8];
  const float* bx_im = (const float*)d_in[9];
  const float* bh_re = (const float*)d_in[10];
  const float* bh_im = (const float*)d_in[11];
  float* out = (float*)d_out;

  char* ws = (char*)d_ws;
  bf16_t* A_big = (bf16_t*)(ws);                         // 67108864 B
  bf16_t* W1t   = (bf16_t*)(ws + 67108864);              // 12582912 B
  bf16_t* A2    = (bf16_t*)(ws + 79691776);              // 33554432 B (rh)
  bf16_t* zbuf  = (bf16_t*)(ws + 113246208);             // 33554432 B (end: 146800640)

  pack_A<<<32768, 256, 0, stream>>>(x_re, x_im, h_re, h_im, A_big);
  pack_W<<<6144, 256, 0, stream>>>(Wx_re, Wx_im, Wh_re, Wh_im, W1t);
  gemm_fused<1><<<512, 512, 0, stream>>>(A_big, W1t, 2048, 2048,
      zbuf, A2, out, h_re, h_im, bx_re, bx_im, bh_re, bh_im);
  gemm_fused<2><<<256, 512, 0, stream>>>(A_big, W1t + (size_t)2048 * 2048, 2048, 2048,
      zbuf, A2, out, h_re, h_im, bx_re, bx_im, bh_re, bh_im);
}

// Round 9
// 511.777 us; speedup vs baseline: 1.4721x; 1.1848x over previous
//
#include <hip/hip_runtime.h>
#include <hip/hip_bf16.h>

typedef __bf16 bf16_t;
typedef __bf16 bf16x8 __attribute__((ext_vector_type(8)));
typedef __bf16 bf16x4 __attribute__((ext_vector_type(4)));
typedef float f32x4 __attribute__((ext_vector_type(4)));

// ---------------------------------------------------------------------------
// Sizes (fixed): B = 16384, D = H = 512
//   A_big : [B][2048] bf16 = [x_re | x_im | h_re | h_im]
//   W1t   : [3072][2048] bf16 (B^T layout), re/im-interleaved output rows:
//           rows [0,1024) z, [1024,2048) r, [2048,3072) u. ALL K=2048:
//           pair 0 = Wx[g] over x-cols, pair 1 = Wh[g] over h-cols.
//           For the u rows (g=2) the "h" operand is rh (stored in A2).
//   A2    : [B][1024] bf16 = [rh_re | rh_im]   (written by gemm1 r-region)
//   zbuf  : [B][1024] bf16 interleaved (z in [0,1]; bf16 quant <= 4e-3, safe)
// u = x.Wx[2] + rh.Wh[2] + b is ONE K=2048 GEMM (gemm2): staging reads
// k-chunks [0,16) from A_big (x part) and [16,32) from A2 (rh part).
// ---------------------------------------------------------------------------

__device__ __forceinline__ void gl_lds16(const bf16_t* g, bf16_t* l) {
  __builtin_amdgcn_global_load_lds(
      (const __attribute__((address_space(1))) void*)g,
      (__attribute__((address_space(3))) void*)l, 16, 0, 0);
}

__device__ __forceinline__ float fast_sigmoid(float x) {
  return 1.0f / (1.0f + __expf(-x));
}

// ---------------------------------------------------------------------------
// Merged pack: blocks [0,32768) pack A_big (8388608 quads); blocks
// [32768,38912) pack W1t (1572864 quads). One launch instead of two.
__global__ void pack_AW(const float* __restrict__ x_re, const float* __restrict__ x_im,
                        const float* __restrict__ h_re, const float* __restrict__ h_im,
                        const float* __restrict__ Wx_re, const float* __restrict__ Wx_im,
                        const float* __restrict__ Wh_re, const float* __restrict__ Wh_im,
                        bf16_t* __restrict__ A, bf16_t* __restrict__ W1t) {
  const int bid = blockIdx.x;
  if (bid < 32768) {
    int q = bid * 256 + threadIdx.x;
    int i4 = q << 2;
    int b = i4 >> 11;
    int k = i4 & 2047;
    int seg = k >> 9;
    int off = k & 511;
    const float* s = (seg == 0) ? x_re : (seg == 1) ? x_im : (seg == 2) ? h_re : h_im;
    const float4 v = *(const float4*)(s + (size_t)b * 512 + off);
    bf16x4 o = { (bf16_t)v.x, (bf16_t)v.y, (bf16_t)v.z, (bf16_t)v.w };
    *(bf16x4*)(A + (size_t)b * 2048 + k) = o;
  } else {
    int q = (bid - 32768) * 256 + threadIdx.x;
    int n = q >> 9;                          // 0..3071
    int k2 = (q & 511) << 2;                 // 0..2044
    int g = n >> 10;                         // gate 0,1,2
    int j = (n & 1023) >> 1;
    int p = n & 1;
    int pair = k2 >> 10;                     // 0: x-part (Wx[g]), 1: h-part (Wh[g])
    const float* Wre = pair ? Wh_re : Wx_re;
    const float* Wim = pair ? Wh_im : Wx_im;
    int klocal = k2 & 1023;
    int half = klocal >> 9;                  // 0: real-operand half, 1: imag half
    int off = klocal & 511;
    size_t sidx = ((size_t)g * 512 + j) * 512 + off;
    const float* s = (half == 0) ? (p ? Wim : Wre) : (p ? Wre : Wim);
    float sgn = (half == 1 && p == 0) ? -1.0f : 1.0f;
    float4 v = *(const float4*)(s + sidx);
    bf16x4 o = { (bf16_t)(sgn * v.x), (bf16_t)(sgn * v.y),
                 (bf16_t)(sgn * v.z), (bf16_t)(sgn * v.w) };
    *(bf16x4*)(W1t + (size_t)n * 2048 + k2) = o;
  }
}

// ---------------------------------------------------------------------------
// 256x256 tile, BK=64, 1024 threads (16 waves, 4M x 4N; per-wave 64x64
// output) -- 4 waves/SIMD, double the independent-progress pool of the
// 8-wave variant (all 6 schedule permutations at 8 waves plateaued at
// ~10K cyc/KT vs 2.5K MFMA floor; this tests the wave-count axis).
// Minimal-sync body (free-skew): per K-tile { stage 4 coarse gl_lds calls
// (kt+1 -> buf^1, each 1024 threads x 16B = 2 sweeps) ; read k0 frags (8 x
// ds_read_b128) ; 16 MFMA ; read k1 ; 16 MFMA ; vmcnt(0) ; barrier }.
// Intra-KT barriers proven valueless; staging targets the other buffer so
// ds_reads race nothing; boundary vmcnt(0) retires loads issued a full KT
// earlier. LDS swizzle: 16B-chunk c ^= (r&7), source-side for gl_lds + on
// ds_read (measured 0 conflicts). Grid decode: xcd=bid&7, idx=bid>>3;
// ntile=idx>>3, mtile=(xcd<<3)+(idx&7) -- keeps per-XCD k-synchronized
// slab reuse (FETCH stays ~compulsory).
// MODE1: 512 blocks (z+r). MODE2: 256 blocks (u); staging selects A_big
// (kt2<16) or A2 (kt2>=16).
template <int MODE>
__launch_bounds__(1024, 4)
__global__ void gemm_fused(const bf16_t* __restrict__ A, const bf16_t* __restrict__ W,
                           int LDA, int LDW,
                           bf16_t* __restrict__ zbuf, bf16_t* __restrict__ A2,
                           float* __restrict__ outbuf,
                           const float* __restrict__ h_re, const float* __restrict__ h_im,
                           const float* __restrict__ bx_re, const float* __restrict__ bx_im,
                           const float* __restrict__ bh_re, const float* __restrict__ bh_im) {
  __shared__ __align__(16) bf16_t As[2][256 * 64];
  __shared__ __align__(16) bf16_t Bs[2][256 * 64];

  const int bid = blockIdx.x;
  const int xcd = bid & 7;
  const int idx = bid >> 3;               // MODE1: 0..63, MODE2: 0..31
  const int ntile = idx >> 3;             // MODE1: 0..7, MODE2: 0..3
  const int mtile = (xcd << 3) + (idx & 7);  // 0..63
  const int m0 = mtile * 256;
  const int n0 = ntile * 256;
  const int region = (MODE == 1) ? (ntile >> 2) : 2;    // 0:z 1:r 2:u
  const int nKT = 32;                     // K = 2048 for all gates

  const int tid = threadIdx.x;
  const int lane = tid & 63;
  const int w = tid >> 6;                 // 0..15
  const int wr = w >> 2;                  // 0..3 (M)
  const int wc = w & 3;                   // 0..3 (N)

  // staging: call s covers rows [128s, 128s+128); thread -> (row rb, chunk cc)
  const int rb = tid >> 3;                // 0..127
  const int cc = tid & 7;                 // 16B chunk within 128B row
  const int cs = cc ^ (rb & 7);           // source-side swizzle
  const bf16_t* Ag = A + (size_t)(m0 + rb) * LDA + cs * 8;
  const bf16_t* Rg = A2 + (size_t)(m0 + rb) * 1024 + cs * 8;   // rh rows (MODE2)
  const bf16_t* Wg = W + (size_t)(n0 + rb) * LDW + cs * 8;

#define STAGE_A(s, bufi, kt2) do {                                            \
    const bf16_t* _g;                                                         \
    if (MODE == 2 && (kt2) >= 16)                                             \
      _g = Rg + (size_t)(s) * 128 * 1024 + ((kt2) - 16) * 64;                 \
    else                                                                      \
      _g = Ag + (size_t)(s) * 128 * LDA + (kt2) * 64;                         \
    gl_lds16(_g, &As[bufi][tid * 8 + (s) * 8192]);                            \
  } while (0)
#define STAGE_B(s, bufi, kt2) \
  gl_lds16(Wg + (size_t)(s) * 128 * LDW + (kt2) * 64, &Bs[bufi][tid * 8 + (s) * 8192])

  const int quad = lane >> 4, lrow = lane & 15;
  int aOff[4], bOff[4];                   // k0 offsets; k1 = off ^ 32
#pragma unroll
  for (int mt = 0; mt < 4; ++mt) {
    const int r = wr * 64 + mt * 16 + lrow;
    aOff[mt] = r * 64 + ((quad ^ (r & 7)) << 3);
  }
#pragma unroll
  for (int nt = 0; nt < 4; ++nt) {
    const int r = wc * 64 + nt * 16 + lrow;
    bOff[nt] = r * 64 + ((quad ^ (r & 7)) << 3);
  }

  f32x4 acc[4][4] = {};

  // prologue: stage KT0 into buf0
  STAGE_B(0, 0, 0); STAGE_B(1, 0, 0);
  STAGE_A(0, 0, 0); STAGE_A(1, 0, 0);
  asm volatile("s_waitcnt vmcnt(0)" ::: "memory");
  __builtin_amdgcn_s_barrier();

  for (int kt = 0; kt < nKT; ++kt) {
    const int b = kt & 1;
    const bf16_t* Ab = As[b];
    const bf16_t* Bb = Bs[b];
    const bool s1 = (kt + 1 < nKT);

    // stage kt+1 into the other buffer (free-skew: races nothing)
    if (s1) {
      STAGE_B(0, b ^ 1, kt + 1); STAGE_B(1, b ^ 1, kt + 1);
      STAGE_A(0, b ^ 1, kt + 1); STAGE_A(1, b ^ 1, kt + 1);
    }

    bf16x8 ak[4], bk[4];

    // ---- k0 half: 8 ds_read_b128 -> 16 MFMA ----
#pragma unroll
    for (int i = 0; i < 4; ++i) bk[i] = *(const bf16x8*)(Bb + bOff[i]);
#pragma unroll
    for (int i = 0; i < 4; ++i) ak[i] = *(const bf16x8*)(Ab + aOff[i]);
    __builtin_amdgcn_s_setprio(1);
#pragma unroll
    for (int i = 0; i < 4; ++i)
#pragma unroll
      for (int j2 = 0; j2 < 4; ++j2)
        acc[i][j2] = __builtin_amdgcn_mfma_f32_16x16x32_bf16(ak[i], bk[j2], acc[i][j2], 0, 0, 0);
    __builtin_amdgcn_s_setprio(0);

    // ---- k1 half ----
#pragma unroll
    for (int i = 0; i < 4; ++i) bk[i] = *(const bf16x8*)(Bb + (bOff[i] ^ 32));
#pragma unroll
    for (int i = 0; i < 4; ++i) ak[i] = *(const bf16x8*)(Ab + (aOff[i] ^ 32));
    __builtin_amdgcn_s_setprio(1);
#pragma unroll
    for (int i = 0; i < 4; ++i)
#pragma unroll
      for (int j2 = 0; j2 < 4; ++j2)
        acc[i][j2] = __builtin_amdgcn_mfma_f32_16x16x32_bf16(ak[i], bk[j2], acc[i][j2], 0, 0, 0);
    __builtin_amdgcn_s_setprio(0);

    // ---- boundary: kt+1's 4 calls (issued a full KT ago) must land ----
    if (s1) asm volatile("s_waitcnt vmcnt(0)" ::: "memory");
    __builtin_amdgcn_s_barrier();
  }
#undef STAGE_A
#undef STAGE_B

  // ---- epilogue ----
  // C/D layout: col = lane&15, row = quad*4 + reg  [verified m89/m91]
#pragma unroll
  for (int mt = 0; mt < 4; ++mt) {
#pragma unroll
    for (int nt = 0; nt < 4; ++nt) {
#pragma unroll
      for (int rg = 0; rg < 4; ++rg) {
        const int m = m0 + wr * 64 + mt * 16 + quad * 4 + rg;
        const int n = n0 + wc * 64 + nt * 16 + lrow;
        float v = acc[mt][nt][rg];
        const int p = n & 1;               // 0 = real component, 1 = imag
        const int cj = n & 1023;
        const int j = cj >> 1;
        const float bias = p ? (bx_im[region * 512 + j] + bh_im[region * 512 + j])
                             : (bx_re[region * 512 + j] + bh_re[region * 512 + j]);
        const float val = v + bias;

        if (MODE == 1) {
          if (region == 0) {               // z gate (bf16 store)
            zbuf[(size_t)m * 1024 + cj] = (bf16_t)fast_sigmoid(val);
          } else {                         // r gate -> rh = r * h (complex)
            float rv = fast_sigmoid(val);
            float ro = __shfl_xor(rv, 1, 64);
            float hp = p ? h_im[(size_t)m * 512 + j] : h_re[(size_t)m * 512 + j];
            float ho = __shfl_xor(hp, 1, 64);
            float rh = (p == 0) ? (rv * hp - ro * ho) : (ro * hp + rv * ho);
            A2[(size_t)m * 1024 + p * 512 + j] = (bf16_t)rh;
          }
        } else {
          // MODE 2: u = val ; h_tilde = tanh(|u|)/|u| * u ; combine
          float u = val;
          float uo = __shfl_xor(u, 1, 64);
          float mag = sqrtf(u * u + uo * uo);
          float mm = fminf(mag, 20.0f);
          float e = __expf(2.0f * mm);
          float th = (e - 1.0f) / (e + 1.0f);
          float s = (mag == 0.0f) ? 0.0f : (th / mag);
          float hto = s * u;               // own component of h_tilde
          float htd = s * uo;              // other component
          float zv = (float)zbuf[(size_t)m * 1024 + cj];
          float zo = __shfl_xor(zv, 1, 64);
          float hp = p ? h_im[(size_t)m * 512 + j] : h_re[(size_t)m * 512 + j];
          float ho = __shfl_xor(hp, 1, 64);
          float res;
          if (p == 0)
            res = (1.0f - zv) * hp + zo * ho + zv * hto - zo * htd;
          else
            res = (1.0f - zo) * hp - zv * ho + zo * hto + zv * htd;
          outbuf[(size_t)m * 1024 + cj] = res;
        }
      }
    }
  }
}

// ---------------------------------------------------------------------------
extern "C" void kernel_launch(void* const* d_in, const int* in_sizes, int n_in,
                              void* d_out, int out_size, void* d_ws, size_t ws_size,
                              hipStream_t stream) {
  const float* x_re  = (const float*)d_in[0];
  const float* x_im  = (const float*)d_in[1];
  const float* h_re  = (const float*)d_in[2];
  const float* h_im  = (const float*)d_in[3];
  const float* Wx_re = (const float*)d_in[4];
  const float* Wx_im = (const float*)d_in[5];
  const float* Wh_re = (const float*)d_in[6];
  const float* Wh_im = (const float*)d_in[7];
  const float* bx_re = (const float*)d_in[8];
  const float* bx_im = (const float*)d_in[9];
  const float* bh_re = (const float*)d_in[10];
  const float* bh_im = (const float*)d_in[11];
  float* out = (float*)d_out;

  char* ws = (char*)d_ws;
  bf16_t* A_big = (bf16_t*)(ws);                         // 67108864 B
  bf16_t* W1t   = (bf16_t*)(ws + 67108864);              // 12582912 B
  bf16_t* A2    = (bf16_t*)(ws + 79691776);              // 33554432 B (rh)
  bf16_t* zbuf  = (bf16_t*)(ws + 113246208);             // 33554432 B (end: 146800640)

  pack_AW<<<38912, 256, 0, stream>>>(x_re, x_im, h_re, h_im,
      Wx_re, Wx_im, Wh_re, Wh_im, A_big, W1t);
  gemm_fused<1><<<512, 1024, 0, stream>>>(A_big, W1t, 2048, 2048,
      zbuf, A2, out, h_re, h_im, bx_re, bx_im, bh_re, bh_im);
  gemm_fused<2><<<256, 1024, 0, stream>>>(A_big, W1t + (size_t)2048 * 2048, 2048, 2048,
      zbuf, A2, out, h_re, h_im, bx_re, bx_im, bh_re, bh_im);
}